// Round 11
// baseline (127.400 us; speedup 1.0000x reference)
//
#include <hip/hip_runtime.h>
#include <hip/hip_bf16.h>
#include <stdint.h>

#define B_  2
#define S_  2048
#define D_  1024
#define H_  16
#define HD_ 64
#define M_  (B_*S_)   // 4096

typedef __bf16 bf16x8 __attribute__((ext_vector_type(8)));
typedef float  f32x4  __attribute__((ext_vector_type(4)));
typedef unsigned int u32x4 __attribute__((ext_vector_type(4)));
typedef unsigned int u32x2 __attribute__((ext_vector_type(2)));
typedef unsigned short ushort_t;
typedef ushort_t u16x8 __attribute__((ext_vector_type(8)));

#define LOG2E 1.44269504088896f

#if __has_builtin(__builtin_amdgcn_exp2f)
#define EXP2(x) __builtin_amdgcn_exp2f(x)
#else
#define EXP2(x) exp2f(x)
#endif

__device__ __forceinline__ ushort_t f2bf(float f) {
    return __builtin_bit_cast(ushort_t, (__bf16)f);
}
__device__ __forceinline__ bf16x8 load_frag(const ushort_t* p) {
    u32x4 r = *reinterpret_cast<const u32x4*>(p);
    return __builtin_bit_cast(bf16x8, r);
}
__device__ __forceinline__ bf16x8 lds_frag(const ushort_t* p) {
    u32x4 r = *reinterpret_cast<const u32x4*>(p);
    return __builtin_bit_cast(bf16x8, r);
}
__device__ __forceinline__ void gld_lds16(const ushort_t* g, ushort_t* l) {
    __builtin_amdgcn_global_load_lds(
        (const __attribute__((address_space(1))) void*)g,
        (__attribute__((address_space(3))) void*)l, 16, 0, 0);
}

// ---------------- f32 -> bf16 conversion (merged, 8 elem/thread) --------
__device__ __forceinline__ void cvt_body(const float* __restrict__ in,
                                         ushort_t* __restrict__ out, int i) {
    f32x4 v0 = *reinterpret_cast<const f32x4*>(in + i);
    f32x4 v1 = *reinterpret_cast<const f32x4*>(in + i + 4);
    u16x8 o;
#pragma unroll
    for (int j = 0; j < 4; ++j) { o[j] = f2bf(v0[j]); o[4 + j] = f2bf(v1[j]); }
    *reinterpret_cast<u16x8*>(out + i) = o;
}

__global__ __launch_bounds__(256) void cvt_all_kernel(
    const float* q, const float* k, const float* v,
    const float* fwq, const float* fwk, const float* fwv, const float* fwo,
    ushort_t* oq, ushort_t* ok, ushort_t* ov,
    ushort_t* owq, ushort_t* owk, ushort_t* owv, ushort_t* owo)
{
    const size_t T = (size_t)M_ * D_;   // 2^22
    const size_t U = (size_t)D_ * D_;   // 2^20
    const size_t idx = ((size_t)blockIdx.x * 256 + threadIdx.x) * 8;
    const float* in; ushort_t* out; size_t off;
    if (idx < 3 * T) {
        const size_t w = idx >> 22; off = idx & (T - 1);
        in  = (w == 0) ? q  : (w == 1) ? k  : v;
        out = (w == 0) ? oq : (w == 1) ? ok : ov;
    } else {
        const size_t r = idx - 3 * T;
        const size_t w = r >> 20; off = r & (U - 1);
        in  = (w == 0) ? fwq : (w == 1) ? fwk : (w == 2) ? fwv : fwo;
        out = (w == 0) ? owq : (w == 1) ? owk : (w == 2) ? owv : owo;
    }
    cvt_body(in, out, (int)off);
}

// ---------------- GEMM: out = X @ W^T + bias ----------------
// Triple-buffered LDS, depth-2 prefetch, counted-vmcnt 2-barrier pipeline.
__device__ __forceinline__ void gemm_body(const ushort_t* __restrict__ X,
                                          const ushort_t* __restrict__ W,
                                          const float* __restrict__ bias,
                                          void* __restrict__ out, int mode)
{
    __shared__ ushort_t lA[3][128 * 32];
    __shared__ ushort_t lB[3][128 * 32];

    const int tid  = threadIdx.x;
    const int lane = tid & 63;
    const int wv   = tid >> 6;
    const int m0   = blockIdx.x * 128;
    const int n0   = blockIdx.y * 128;
    const int wr   = (wv >> 1) * 64;
    const int wc   = (wv & 1) * 64;
    const int l15  = lane & 15;
    const int lg   = lane >> 4;

    f32x4 acc[4][4];
#pragma unroll
    for (int i = 0; i < 4; ++i)
#pragma unroll
        for (int j = 0; j < 4; ++j) acc[i][j] = (f32x4){0.f, 0.f, 0.f, 0.f};

    const int srow = lane >> 2;
    const int sk   = (lane & 3) * 8;
    const int c0   = wv * 2, c1 = wv * 2 + 1;
    const size_t arow0 = (size_t)(m0 + c0 * 16 + srow) * D_ + sk;
    const size_t arow1 = (size_t)(m0 + c1 * 16 + srow) * D_ + sk;
    const size_t brow0 = (size_t)(n0 + c0 * 16 + srow) * D_ + sk;
    const size_t brow1 = (size_t)(n0 + c1 * 16 + srow) * D_ + sk;

    auto stage = [&](int ktile, int bufi) {
        const int k0 = ktile * 32;
        gld_lds16(X + arow0 + k0, &lA[bufi][c0 * 512]);
        gld_lds16(X + arow1 + k0, &lA[bufi][c1 * 512]);
        gld_lds16(W + brow0 + k0, &lB[bufi][c0 * 512]);
        gld_lds16(W + brow1 + k0, &lB[bufi][c1 * 512]);
    };

    const int NKT = D_ / 32;
    stage(0, 0);
    stage(1, 1);

    int cur = 0;
    for (int kt = 0; kt < NKT; ++kt) {
        __builtin_amdgcn_s_barrier();
        if (kt + 2 < NKT) {
            int nxt = cur + 2; if (nxt >= 3) nxt -= 3;
            stage(kt + 2, nxt);
            asm volatile("s_waitcnt vmcnt(8)" ::: "memory");
        } else if (kt + 2 == NKT) {
            asm volatile("s_waitcnt vmcnt(4)" ::: "memory");
        } else {
            asm volatile("s_waitcnt vmcnt(0)" ::: "memory");
        }
        __builtin_amdgcn_s_barrier();
        __builtin_amdgcn_sched_barrier(0);

        bf16x8 a[4], b[4];
#pragma unroll
        for (int i = 0; i < 4; ++i)
            a[i] = lds_frag(&lA[cur][(wr + i * 16 + l15) * 32 + lg * 8]);
#pragma unroll
        for (int j = 0; j < 4; ++j)
            b[j] = lds_frag(&lB[cur][(wc + j * 16 + l15) * 32 + lg * 8]);
#pragma unroll
        for (int i = 0; i < 4; ++i)
#pragma unroll
            for (int j = 0; j < 4; ++j)
                acc[i][j] = __builtin_amdgcn_mfma_f32_16x16x32_bf16(a[i], b[j], acc[i][j], 0, 0, 0);

        cur = (cur == 2) ? 0 : cur + 1;
    }

#pragma unroll
    for (int i = 0; i < 4; ++i) {
#pragma unroll
        for (int j = 0; j < 4; ++j) {
            const int gcol = n0 + wc + j * 16 + l15;
            const float bv = bias[gcol];
#pragma unroll
            for (int r = 0; r < 4; ++r) {
                const int grow = m0 + wr + i * 16 + lg * 4 + r;
                float v = acc[i][j][r] + bv;
                if (mode == 0) v *= 0.125f * LOG2E;
                if (mode == 3) {
                    ((float*)out)[(size_t)grow * D_ + gcol] = v;
                } else {
                    const int b = grow >> 11, s = grow & (S_ - 1);
                    const int h = gcol >> 6,  hd = gcol & 63;
                    size_t addr;
                    if (mode == 2) addr = ((size_t)(b * H_ + h) * HD_ + hd) * S_ + s;
                    else           addr = ((size_t)(b * H_ + h) * S_ + s) * HD_ + hd;
                    ((ushort_t*)out)[addr] = f2bf(v);
                }
            }
        }
    }
}

__global__ __launch_bounds__(256) void qkv_kernel(
    const ushort_t* q_in, const ushort_t* k_in, const ushort_t* v_in,
    const ushort_t* Wq, const ushort_t* Wk, const ushort_t* Wv,
    const float* bq, const float* bk, const float* bv,
    ushort_t* qo, ushort_t* ko, ushort_t* vo)
{
    const int z = blockIdx.z;
    const ushort_t* X  = (z == 0) ? q_in : (z == 1) ? k_in : v_in;
    const ushort_t* W  = (z == 0) ? Wq   : (z == 1) ? Wk   : Wv;
    const float*    bs = (z == 0) ? bq   : (z == 1) ? bk   : bv;
    ushort_t*       o  = (z == 0) ? qo   : (z == 1) ? ko   : vo;
    gemm_body(X, W, bs, o, (z == 2) ? 2 : z);
}

__global__ __launch_bounds__(256) void oproj_kernel(
    const ushort_t* X, const ushort_t* W, const float* bias, float* out)
{
    gemm_body(X, W, bias, out, 3);
}

// ---------------- Flash attention (deferred-PV pipeline) ----------------
// Q (pre-scaled 0.125*log2e), K: [B,H,S,HD] bf16. VT: [B,H,HD,S] bf16.
// O: [B,S,D] bf16. grid (bh, qb); 8 waves = (wq 0..3) x (wkv 0..1), wave
// owns a 32q x 32kv quadrant. Iteration t computes QK^T(t) AND PV(t-1):
// PV's inputs (P in wave-private LDS dbuf, V staged 1 tile back) are ready
// at region start, so PV MFMAs fill the QK^T->exp2 serial-chain shadow.
// Unconditional staging (K(NT) over-read lands in ws, unused). vmcnt(2)
// constant in-loop. No-max softmax (exp2 domain), kv-partials combined in
// LDS at epilogue.
#define PST2 40
#define KVB 64
#define NT  (S_ / KVB)
// smem carve (ushorts)
#define SM_K0 0
#define SM_K1 4096
#define SM_V0 8192
#define SM_V1 12288
#define SM_P0 16384
#define SM_P1 26624
#define SM_TOT 36864   // 72 KB

__global__ __launch_bounds__(512, 4) void attn_kernel(
    const ushort_t* __restrict__ Q, const ushort_t* __restrict__ K,
    const ushort_t* __restrict__ VT, ushort_t* __restrict__ O)
{
    __shared__ ushort_t smem[SM_TOT];

    const int lane = threadIdx.x & 63;
    const int wv   = threadIdx.x >> 6;    // 0..7
    const int wq   = wv & 3;              // q-group
    const int wkv  = wv >> 2;             // kv-half
    const int bh   = blockIdx.x;
    const int qb   = blockIdx.y;          // 0..15
    const int qbase = qb * 128 + wq * 32;
    const int l15  = lane & 15;
    const int lg   = lane >> 4;

    const ushort_t* Qp = Q  + (size_t)bh * S_ * HD_;
    const ushort_t* Kp = K  + (size_t)bh * S_ * HD_;
    const ushort_t* Vp = VT + (size_t)bh * HD_ * S_;

    // staging: 512 threads, 1 K chunk + 1 V chunk (16B each)
    const int kr = threadIdx.x >> 3;
    const int kc = ((threadIdx.x & 7) ^ (kr & 7)) * 8;
    const int koff = threadIdx.x * 8;

    auto stageK = [&](int tile, ushort_t* kdst) {
        gld_lds16(Kp + (size_t)(tile * KVB + kr) * HD_ + kc, kdst + koff);
    };
    auto stageV = [&](int tile, ushort_t* vdst) {
        gld_lds16(Vp + (size_t)kr * S_ + tile * KVB + kc, vdst + koff);
    };

    // swizzled fragment offsets
    int offk[2][2];   // K rows wkv*32 + j*16 + l15, cols c*32+lg*8
#pragma unroll
    for (int j = 0; j < 2; ++j)
#pragma unroll
        for (int c = 0; c < 2; ++c)
            offk[j][c] = (wkv * 32 + j * 16 + l15) * 64 +
                         ((c * 32 + lg * 8) ^ ((l15 & 7) << 3));
    int offv[4];      // V rows dt*16 + l15, cols wkv*32 + lg*8
#pragma unroll
    for (int dt = 0; dt < 4; ++dt)
        offv[dt] = (dt * 16 + l15) * 64 +
                   ((wkv * 32 + lg * 8) ^ ((l15 & 7) << 3));

    // Q fragments (B-operand: lane&15 = q-row)
    bf16x8 aq[2][2];
#pragma unroll
    for (int qh = 0; qh < 2; ++qh)
#pragma unroll
        for (int c = 0; c < 2; ++c)
            aq[c][qh] = load_frag(Qp + (size_t)(qbase + qh * 16 + l15) * HD_ + c * 32 + lg * 8);

    f32x4 accO[4][2];   // O^T partial (this wkv half)
#pragma unroll
    for (int dt = 0; dt < 4; ++dt)
#pragma unroll
        for (int qh = 0; qh < 2; ++qh) accO[dt][qh] = (f32x4){0.f, 0.f, 0.f, 0.f};
    float lrun0 = 0.f, lrun1 = 0.f;

    ushort_t* pA = &smem[SM_P0 + wv * 32 * PST2];   // P even tiles
    ushort_t* pB = &smem[SM_P1 + wv * 32 * PST2];   // P odd tiles

    // softmax+pack helper used per tile
    auto softmax_pack = [&](f32x4 st[2][2], ushort_t* pw) {
#pragma unroll
        for (int qh = 0; qh < 2; ++qh) {
            float p[2][4];
#pragma unroll
            for (int j = 0; j < 2; ++j)
#pragma unroll
                for (int r = 0; r < 4; ++r)
                    p[j][r] = EXP2(st[j][qh][r]);
#pragma unroll
            for (int j = 0; j < 2; ++j) {
                u32x2 w;
                w[0] = (unsigned)f2bf(p[j][0]) | ((unsigned)f2bf(p[j][1]) << 16);
                w[1] = (unsigned)f2bf(p[j][2]) | ((unsigned)f2bf(p[j][3]) << 16);
                *reinterpret_cast<u32x2*>(
                    &pw[(qh * 16 + l15) * PST2 + j * 16 + lg * 4]) = w;
            }
            float s0 = (p[0][0] + p[0][1]) + (p[0][2] + p[0][3]);
            float s1 = (p[1][0] + p[1][1]) + (p[1][2] + p[1][3]);
            if (qh == 0) lrun0 += s0 + s1;
            else         lrun1 += s0 + s1;
        }
    };

    // ---------------- prologue: K(0) ----------------
    stageK(0, &smem[SM_K0]);

    // ---------------- iter 0 (peeled: QK^T(0) only) ----------------
    {
        __builtin_amdgcn_s_barrier();
        stageK(1, &smem[SM_K1]);
        stageV(0, &smem[SM_V0]);
        asm volatile("s_waitcnt vmcnt(2)" ::: "memory");
        __builtin_amdgcn_s_barrier();
        __builtin_amdgcn_sched_barrier(0);

        const ushort_t* kb = &smem[SM_K0];
        f32x4 st[2][2];
#pragma unroll
        for (int j = 0; j < 2; ++j)
#pragma unroll
            for (int qh = 0; qh < 2; ++qh) st[j][qh] = (f32x4){0.f, 0.f, 0.f, 0.f};
        __builtin_amdgcn_s_setprio(1);
#pragma unroll
        for (int j = 0; j < 2; ++j) {
            bf16x8 k0 = lds_frag(&kb[offk[j][0]]);
            bf16x8 k1 = lds_frag(&kb[offk[j][1]]);
            st[j][0] = __builtin_amdgcn_mfma_f32_16x16x32_bf16(k0, aq[0][0], st[j][0], 0, 0, 0);
            st[j][0] = __builtin_amdgcn_mfma_f32_16x16x32_bf16(k1, aq[1][0], st[j][0], 0, 0, 0);
            st[j][1] = __builtin_amdgcn_mfma_f32_16x16x32_bf16(k0, aq[0][1], st[j][1], 0, 0, 0);
            st[j][1] = __builtin_amdgcn_mfma_f32_16x16x32_bf16(k1, aq[1][1], st[j][1], 0, 0, 0);
        }
        __builtin_amdgcn_s_setprio(0);
        softmax_pack(st, pA);
    }

    // ---------------- main loop: QK^T(t) + PV(t-1) ----------------
    for (int t = 1; t < NT; ++t) {
        const int cur = t & 1;
        const ushort_t* kb  = cur ? &smem[SM_K1] : &smem[SM_K0];
        const ushort_t* vbp = cur ? &smem[SM_V0] : &smem[SM_V1];  // V(t-1)
        ushort_t* pw = cur ? pB : pA;        // write P(t)
        const ushort_t* pr = cur ? pA : pB;  // read  P(t-1)

        __builtin_amdgcn_s_barrier();        // readers of target bufs done
        stageK(t + 1, cur ? &smem[SM_K0] : &smem[SM_K1]);  // K(NT) over-read ok
        stageV(t, cur ? &smem[SM_V1] : &smem[SM_V0]);
        asm volatile("s_waitcnt vmcnt(2)" ::: "memory");   // K(t),V(t-1) landed
        __builtin_amdgcn_s_barrier();
        __builtin_amdgcn_sched_barrier(0);

        // P(t-1) fragments (wave-private)
        bf16x8 ap[2];
#pragma unroll
        for (int qh = 0; qh < 2; ++qh)
            ap[qh] = lds_frag(&pr[(qh * 16 + l15) * PST2 + lg * 8]);

        f32x4 st[2][2];
#pragma unroll
        for (int j = 0; j < 2; ++j)
#pragma unroll
            for (int qh = 0; qh < 2; ++qh) st[j][qh] = (f32x4){0.f, 0.f, 0.f, 0.f};

        __builtin_amdgcn_s_setprio(1);
        // QK^T(t)
#pragma unroll
        for (int j = 0; j < 2; ++j) {
            bf16x8 k0 = lds_frag(&kb[offk[j][0]]);
            bf16x8 k1 = lds_frag(&kb[offk[j][1]]);
            st[j][0] = __builtin_amdgcn_mfma_f32_16x16x32_bf16(k0, aq[0][0], st[j][0], 0, 0, 0);
            st[j][0] = __builtin_amdgcn_mfma_f32_16x16x32_bf16(k1, aq[1][0], st[j][0], 0, 0, 0);
            st[j][1] = __builtin_amdgcn_mfma_f32_16x16x32_bf16(k0, aq[0][1], st[j][1], 0, 0, 0);
            st[j][1] = __builtin_amdgcn_mfma_f32_16x16x32_bf16(k1, aq[1][1], st[j][1], 0, 0, 0);
        }
        // PV(t-1) — independent of QK^T(t)/exp2(t): fills their shadow
#pragma unroll
        for (int dt = 0; dt < 4; ++dt) {
            bf16x8 vf = lds_frag(&vbp[offv[dt]]);
            accO[dt][0] = __builtin_amdgcn_mfma_f32_16x16x32_bf16(vf, ap[0], accO[dt][0], 0, 0, 0);
            accO[dt][1] = __builtin_amdgcn_mfma_f32_16x16x32_bf16(vf, ap[1], accO[dt][1], 0, 0, 0);
        }
        __builtin_amdgcn_s_setprio(0);

        softmax_pack(st, pw);
    }

    // ---------------- epilogue: PV(NT-1) ----------------
    {
        asm volatile("s_waitcnt vmcnt(0)" ::: "memory");   // own V(NT-1) landed
        __builtin_amdgcn_s_barrier();                      // all waves landed
        const ushort_t* vbp = ((NT - 1) & 1) ? &smem[SM_V1] : &smem[SM_V0];
        const ushort_t* pr  = ((NT - 1) & 1) ? pB : pA;
        bf16x8 ap[2];
#pragma unroll
        for (int qh = 0; qh < 2; ++qh)
            ap[qh] = lds_frag(&pr[(qh * 16 + l15) * PST2 + lg * 8]);
#pragma unroll
        for (int dt = 0; dt < 4; ++dt) {
            bf16x8 vf = lds_frag(&vbp[offv[dt]]);
            accO[dt][0] = __builtin_amdgcn_mfma_f32_16x16x32_bf16(vf, ap[0], accO[dt][0], 0, 0, 0);
            accO[dt][1] = __builtin_amdgcn_mfma_f32_16x16x32_bf16(vf, ap[1], accO[dt][1], 0, 0, 0);
        }
    }

    // ---- reduce over lg, combine wkv pair via LDS, write O ----
    lrun0 += __shfl_xor(lrun0, 16);
    lrun0 += __shfl_xor(lrun0, 32);
    lrun1 += __shfl_xor(lrun1, 16);
    lrun1 += __shfl_xor(lrun1, 32);

    __syncthreads();   // all tile reads done; smem reusable
    float* cbuf = (float*)smem;   // [128 rows][68 f32] + 128 lrun slots

    if (wkv == 1) {
#pragma unroll
        for (int qh = 0; qh < 2; ++qh) {
            const int rowq = (wq * 2 + qh) * 16 + l15;
#pragma unroll
            for (int dt = 0; dt < 4; ++dt)
                *reinterpret_cast<f32x4*>(&cbuf[rowq * 68 + dt * 16 + lg * 4]) = accO[dt][qh];
        }
        if (lane < 16) {
            cbuf[128 * 68 + (wq * 2 + 0) * 16 + lane] = lrun0;
            cbuf[128 * 68 + (wq * 2 + 1) * 16 + lane] = lrun1;
        }
    }
    __syncthreads();

    if (wkv == 0) {
        const int b = bh >> 4, h = bh & 15;
#pragma unroll
        for (int qh = 0; qh < 2; ++qh) {
            const int rowq = (wq * 2 + qh) * 16 + l15;
            const float lsum = (qh == 0 ? lrun0 : lrun1) + cbuf[128 * 68 + rowq];
            const float inv = 1.0f / lsum;
            const size_t rowbase =
                (size_t)(b * S_ + qbase + qh * 16 + l15) * D_ + h * 64;
#pragma unroll
            for (int dt = 0; dt < 4; ++dt) {
                f32x4 part = *reinterpret_cast<f32x4*>(&cbuf[rowq * 68 + dt * 16 + lg * 4]);
                f32x4 tot  = accO[dt][qh] + part;
                u32x2 w;
                w[0] = (unsigned)f2bf(tot[0] * inv) | ((unsigned)f2bf(tot[1] * inv) << 16);
                w[1] = (unsigned)f2bf(tot[2] * inv) | ((unsigned)f2bf(tot[3] * inv) << 16);
                *reinterpret_cast<u32x2*>(&O[rowbase + dt * 16 + lg * 4]) = w;
            }
        }
    }
}

// ---------------- host launch ----------------
extern "C" void kernel_launch(void* const* d_in, const int* in_sizes, int n_in,
                              void* d_out, int out_size, void* d_ws, size_t ws_size,
                              hipStream_t stream)
{
    const float* query = (const float*)d_in[0];
    const float* key_  = (const float*)d_in[1];
    const float* value = (const float*)d_in[2];
    const float* Wq    = (const float*)d_in[3];
    const float* bq    = (const float*)d_in[4];
    const float* Wk    = (const float*)d_in[5];
    const float* bk    = (const float*)d_in[6];
    const float* Wv    = (const float*)d_in[7];
    const float* bv    = (const float*)d_in[8];
    const float* Wo    = (const float*)d_in[9];
    const float* bo    = (const float*)d_in[10];

    ushort_t* ws   = (ushort_t*)d_ws;
    const size_t T = (size_t)M_ * D_;
    const size_t U = (size_t)D_ * D_;
    ushort_t* xq  = ws;
    ushort_t* xk  = xq + T;
    ushort_t* xv  = xk + T;
    ushort_t* wq  = xv + T;
    ushort_t* wk  = wq + U;
    ushort_t* wv  = wk + U;
    ushort_t* wo  = wv + U;
    ushort_t* qws  = wo + U;            // [B,H,S,HD] (pre-scaled)
    ushort_t* kws  = qws + T;           // [B,H,S,HD]
    ushort_t* vtws = kws + T;           // [B,H,HD,S]
    ushort_t* aows = vtws + T;          // [B,S,D]

    const int cvt_blocks = (int)((3 * T + 4 * U) / (256 * 8));   // 8192
    cvt_all_kernel<<<cvt_blocks, 256, 0, stream>>>(
        query, key_, value, Wq, Wk, Wv, Wo,
        xq, xk, xv, wq, wk, wv, wo);

    qkv_kernel<<<dim3(32, 8, 3), 256, 0, stream>>>(
        xq, xk, xv, wq, wk, wv, bq, bk, bv, qws, kws, vtws);

    attn_kernel<<<dim3(32, 16), 512, 0, stream>>>(qws, kws, vtws, aows);

    oproj_kernel<<<dim3(32, 8, 1), 256, 0, stream>>>(
        aows, wo, bo, (float*)d_out);
}